// Round 2
// 187.899 us; speedup vs baseline: 1.0024x; 1.0024x over previous
//
#include <hip/hip_runtime.h>

#define N_NODES 50000
#define N_EDGES 800000
#define IN_DIM 16
#define OUT_DIM 16
#define N_RELS 90
#define N_BASES 30

#define CAP 64          // 8B entries -> 512B/node row; P(deg>64 | Poisson 16) ~ 0
#define LDS_STRIDE 260  // 256 + 4 pad (16B-aligned rows)

#define PREP_BLOCKS 91   // 91*256 = 23296 >= 23088
#define DOTS_BLOCKS 196  // 196*256 = 50176 >= 50000
#define ZERO_BLOCKS 196
#define HZ_BLOCKS 782    // 782*256 float4 >= 200000 float4 (zero hout)

#define NODES_PER_RBLK 256  // reduce_bmm: 1024 thr / 4 lanes-per-node

__device__ __forceinline__ float4 shfl_xor4(float4 v, int m) {
    float4 r;
    r.x = __shfl_xor(v.x, m); r.y = __shfl_xor(v.y, m);
    r.z = __shfl_xor(v.z, m); r.w = __shfl_xor(v.w, m);
    return r;
}

// ---------------------------------------------------------------------------
// Setup: [0,91) prep Wrel+avec; [91,287) node dots s13; [287,483) zero cnt;
// [483,1265) zero hout.
// ---------------------------------------------------------------------------
__global__ __launch_bounds__(256) void setup_kernel(
    const float* __restrict__ Ws,
    const float* __restrict__ Wa,
    const float* __restrict__ weight,
    const float* __restrict__ w_comp,
    const float* __restrict__ h,
    float* __restrict__ Wrel,
    float* __restrict__ avec,
    float2* __restrict__ s13,
    int* __restrict__ cnt,
    float* __restrict__ hout)
{
    int b = blockIdx.x;
    if (b < PREP_BLOCKS) {
        int f = b * 256 + threadIdx.x;
        if (f < N_RELS * IN_DIM * OUT_DIM) {
            int a   = f / (N_RELS * OUT_DIM);
            int rem = f % (N_RELS * OUT_DIM);
            int r   = rem / OUT_DIM;
            int o   = rem % OUT_DIM;
            float acc = 0.f;
            #pragma unroll
            for (int bb = 0; bb < N_BASES; ++bb)
                acc += w_comp[r * N_BASES + bb] * weight[a * (N_BASES * OUT_DIM) + bb * OUT_DIM + o];
            Wrel[f] = acc;
        } else if (f < N_RELS * IN_DIM * OUT_DIM + 48) {
            int g = f - N_RELS * IN_DIM * OUT_DIM;
            int k = g / IN_DIM;
            int i = g % IN_DIM;
            float acc = 0.f;
            #pragma unroll
            for (int o = 0; o < OUT_DIM; ++o)
                acc += Wa[k * OUT_DIM + o] * Ws[o * IN_DIM + i];
            avec[g] = acc;
        }
    } else if (b < PREP_BLOCKS + DOTS_BLOCKS) {
        __shared__ float la[48];
        if (threadIdx.x < 48) {
            int k = threadIdx.x / IN_DIM;
            int i = threadIdx.x % IN_DIM;
            float acc = 0.f;
            #pragma unroll
            for (int o = 0; o < OUT_DIM; ++o)
                acc += Wa[k * OUT_DIM + o] * Ws[o * IN_DIM + i];
            la[threadIdx.x] = acc;
        }
        __syncthreads();
        int n = (b - PREP_BLOCKS) * 256 + threadIdx.x;
        if (n >= N_NODES) return;
        const float4* p = (const float4*)(h + (size_t)n * IN_DIM);
        float d1 = 0.f, d3 = 0.f;
        #pragma unroll
        for (int i = 0; i < 4; ++i) {
            float4 v = p[i];
            d1 += v.x * la[4*i+0] + v.y * la[4*i+1] + v.z * la[4*i+2] + v.w * la[4*i+3];
            d3 += v.x * la[32+4*i+0] + v.y * la[32+4*i+1] + v.z * la[32+4*i+2] + v.w * la[32+4*i+3];
        }
        s13[n] = make_float2(d1, d3);
    } else if (b < PREP_BLOCKS + DOTS_BLOCKS + ZERO_BLOCKS) {
        int n = (b - PREP_BLOCKS - DOTS_BLOCKS) * 256 + threadIdx.x;
        if (n < N_NODES) cnt[n] = 0;
    } else {
        int idx = (b - PREP_BLOCKS - DOTS_BLOCKS - ZERO_BLOCKS) * 256 + threadIdx.x;
        if (idx < N_NODES * OUT_DIM / 4) {
            float4 z = {0.f, 0.f, 0.f, 0.f};
            ((float4*)hout)[idx] = z;
        }
    }
}

// ---------------------------------------------------------------------------
// Route: one thread per edge. Compute attention score only (he dot + two
// L2-resident s13 gathers) and scatter an 8-byte entry {(rel<<16)|src, score}
// into the destination node's bucket row. No LDS, no Wrel -> full occupancy,
// pure he stream. Overflow (slot >= CAP, expected never): full matmul from
// global Wrel + atomicAdd into pre-zeroed hout.
// ---------------------------------------------------------------------------
__global__ __launch_bounds__(256) void route_kernel(
    const float* __restrict__ h,
    const float* __restrict__ he,
    const int* __restrict__ src,
    const int* __restrict__ dst,
    const int* __restrict__ rel,
    const float* __restrict__ Wrel,
    const float* __restrict__ avec,
    const float2* __restrict__ s13,
    int* __restrict__ cnt,
    uint2* __restrict__ bucket,
    float* __restrict__ hout)
{
    int e = blockIdx.x * 256 + threadIdx.x;
    if (e >= N_EDGES) return;
    int s = src[e], d = dst[e], r = rel[e];

    const float4* hep = (const float4*)(he + (size_t)e * IN_DIM);
    const float4* ap  = (const float4*)(avec + 16);
    float pd = 0.f;
    #pragma unroll
    for (int i = 0; i < 4; ++i) {
        float4 v = hep[i];
        float4 a = ap[i];
        pd += v.x * a.x + v.y * a.y + v.z * a.z + v.w * a.w;
    }
    float2 ss = s13[s];
    float2 sd = s13[d];
    float score = ss.x + sd.y + pd;

    int slot = atomicAdd(&cnt[d], 1);
    if (slot < CAP) {
        uint2 ent;
        ent.x = ((unsigned)r << 16) | (unsigned)s;   // s < 50000 < 2^16, r < 90 < 2^7
        ent.y = __float_as_uint(score);
        bucket[(size_t)d * CAP + slot] = ent;
    } else {
        // rare/never: compute the full message here from global Wrel (L2-hot)
        float hs[16];
        const float4* hp = (const float4*)(h + (size_t)s * IN_DIM);
        #pragma unroll
        for (int i = 0; i < 4; ++i) {
            float4 v = hp[i];
            hs[4*i+0] = v.x; hs[4*i+1] = v.y; hs[4*i+2] = v.z; hs[4*i+3] = v.w;
        }
        const float* W = Wrel + (size_t)r * 256;
        float* outp = hout + (size_t)d * OUT_DIM;
        #pragma unroll
        for (int o = 0; o < OUT_DIM; ++o) {
            float acc = 0.f;
            #pragma unroll
            for (int i = 0; i < IN_DIM; ++i) acc += hs[i] * W[i * OUT_DIM + o];
            atomicAdd(outp + o, acc * score);
        }
    }
}

// ---------------------------------------------------------------------------
// Reduce+BMM: 4 lanes per node (q = output quarter), 256 nodes per 1024-thread
// block, Wrel staged once in LDS (padded stride). Per entry: 8B bucket read
// (L1-resident line per node), h[src] gather (L2-resident 3.2MB), shfl
// transpose, 16x ds_read_b128 bmm, accumulate node row IN REGISTERS.
// Messages never touch global memory. 4-entry batching for MLP.
// ---------------------------------------------------------------------------
__global__ __launch_bounds__(1024) void reduce_bmm_kernel(
    const float* __restrict__ h,
    const float* __restrict__ Wrel,
    const uint2* __restrict__ bucket,
    const int* __restrict__ cnt,
    float* __restrict__ hout)
{
    extern __shared__ float lw[];   // [N_RELS * LDS_STRIDE]
    for (int j = threadIdx.x; j < N_RELS * 64; j += 1024) {
        int r = j >> 6;
        int w = j & 63;
        float4 v = ((const float4*)Wrel)[r * 64 + w];
        *(float4*)(lw + r * LDS_STRIDE + w * 4) = v;
    }
    __syncthreads();

    int n = blockIdx.x * NODES_PER_RBLK + (threadIdx.x >> 2);
    int q = threadIdx.x & 3;
    if (n >= N_NODES) return;

    int deg = cnt[n];
    int m = deg > CAP ? CAP : deg;
    const uint2* ep = bucket + (size_t)n * CAP;
    float4 acc = {0.f, 0.f, 0.f, 0.f};

    for (int j0 = 0; j0 < m; j0 += 4) {
        uint2 ent[4];
        float4 hq[4];
        bool val[4];

        // [1] entry loads (same 8B addr for the 4 q-lanes -> broadcast; the
        //     node's 16-entry 128B line stays in L1 across macro-iters).
        //     Invalid k clamps to the last valid entry (j0 < m here, so
        //     min(j, m-1) is always an initialized, in-bounds slot).
        #pragma unroll
        for (int k = 0; k < 4; ++k) {
            int j = j0 + k;
            val[k] = (j < m);
            int jc = j < m ? j : (m - 1);
            ent[k] = ep[jc];
        }

        // [2] h gathers (4 independent chains)
        #pragma unroll
        for (int k = 0; k < 4; ++k) {
            int s = ent[k].x & 0xFFFF;
            hq[k] = *(const float4*)(h + (size_t)s * IN_DIM + q * 4);
        }

        // [3] process (val[k] uniform within the 4-lane quad -> shfl safe)
        #pragma unroll
        for (int k = 0; k < 4; ++k) {
            if (!val[k]) continue;
            int r = ent[k].x >> 16;
            float score = __uint_as_float(ent[k].y);

            float4 o1 = shfl_xor4(hq[k], 1);
            float4 o2 = shfl_xor4(hq[k], 2);
            float4 o3 = shfl_xor4(o1, 2);
            bool q0 = (q == 0), q1 = (q == 1), q2 = (q == 2);
            float4 row0 = q0 ? hq[k] : q1 ? o1 : q2 ? o2 : o3;
            float4 row1 = q0 ? o1 : q1 ? hq[k] : q2 ? o3 : o2;
            float4 row2 = q0 ? o2 : q1 ? o3 : q2 ? hq[k] : o1;
            float4 row3 = q0 ? o3 : q1 ? o2 : q2 ? o1 : hq[k];
            float hs[16] = {row0.x,row0.y,row0.z,row0.w, row1.x,row1.y,row1.z,row1.w,
                            row2.x,row2.y,row2.z,row2.w, row3.x,row3.y,row3.z,row3.w};

            const float* wb = lw + (size_t)r * LDS_STRIDE + q * 4;
            float4 a = {0.f, 0.f, 0.f, 0.f};
            #pragma unroll
            for (int i = 0; i < 16; ++i) {
                float4 w = *(const float4*)(wb + i * 16);
                float hv = hs[i];
                a.x += hv * w.x; a.y += hv * w.y; a.z += hv * w.z; a.w += hv * w.w;
            }
            acc.x += score * a.x; acc.y += score * a.y;
            acc.z += score * a.z; acc.w += score * a.w;
        }
    }

    float* outp = hout + (size_t)n * OUT_DIM + q * 4;
    if (deg <= CAP) {
        *(float4*)outp = acc;
    } else {
        atomicAdd(outp + 0, acc.x);
        atomicAdd(outp + 1, acc.y);
        atomicAdd(outp + 2, acc.z);
        atomicAdd(outp + 3, acc.w);
    }
}

// ===========================================================================
// Fallback (ws too small): direct atomic scatter (known-correct).
// ===========================================================================
__global__ __launch_bounds__(256) void prep_kernel(
    const float* __restrict__ Ws, const float* __restrict__ Wa,
    const float* __restrict__ weight, const float* __restrict__ w_comp,
    float* __restrict__ Wrel, float* __restrict__ avec)
{
    int f = blockIdx.x * blockDim.x + threadIdx.x;
    if (f < N_RELS * IN_DIM * OUT_DIM) {
        int a   = f / (N_RELS * OUT_DIM);
        int rem = f % (N_RELS * OUT_DIM);
        int r   = rem / OUT_DIM;
        int o   = rem % OUT_DIM;
        float acc = 0.f;
        #pragma unroll
        for (int b = 0; b < N_BASES; ++b)
            acc += w_comp[r * N_BASES + b] * weight[a * (N_BASES * OUT_DIM) + b * OUT_DIM + o];
        Wrel[f] = acc;
    } else if (f < N_RELS * IN_DIM * OUT_DIM + 48) {
        int g = f - N_RELS * IN_DIM * OUT_DIM;
        int k = g / IN_DIM;
        int i = g % IN_DIM;
        float acc = 0.f;
        #pragma unroll
        for (int o = 0; o < OUT_DIM; ++o)
            acc += Wa[k * OUT_DIM + o] * Ws[o * IN_DIM + i];
        avec[g] = acc;
    }
}

__global__ __launch_bounds__(256) void edge_atomic_kernel(
    const float* __restrict__ h,
    const float* __restrict__ he,
    const int* __restrict__ src,
    const int* __restrict__ dst,
    const int* __restrict__ rel,
    const float* __restrict__ Wrel,
    const float* __restrict__ avec,
    float* __restrict__ hout)
{
    int e = blockIdx.x * blockDim.x + threadIdx.x;
    if (e >= N_EDGES) return;
    int s = src[e], d = dst[e], r = rel[e];
    float hs[IN_DIM];
    const float4* p = (const float4*)(h + (size_t)s * IN_DIM);
    #pragma unroll
    for (int i = 0; i < 4; ++i) {
        float4 v = p[i];
        hs[4*i+0] = v.x; hs[4*i+1] = v.y; hs[4*i+2] = v.z; hs[4*i+3] = v.w;
    }
    float score = 0.f;
    #pragma unroll
    for (int i = 0; i < IN_DIM; ++i) score += hs[i] * avec[i];
    const float4* qe = (const float4*)(he + (size_t)e * IN_DIM);
    #pragma unroll
    for (int i = 0; i < 4; ++i) {
        float4 v = qe[i];
        score += v.x * avec[16+4*i] + v.y * avec[17+4*i] + v.z * avec[18+4*i] + v.w * avec[19+4*i];
    }
    const float4* pd = (const float4*)(h + (size_t)d * IN_DIM);
    #pragma unroll
    for (int i = 0; i < 4; ++i) {
        float4 v = pd[i];
        score += v.x * avec[32+4*i] + v.y * avec[33+4*i] + v.z * avec[34+4*i] + v.w * avec[35+4*i];
    }
    float acc[OUT_DIM];
    #pragma unroll
    for (int o = 0; o < OUT_DIM; ++o) acc[o] = 0.f;
    const float* W = Wrel + (size_t)r * 256;
    #pragma unroll
    for (int i = 0; i < IN_DIM; ++i) {
        float hv = hs[i];
        #pragma unroll
        for (int o = 0; o < OUT_DIM; ++o) acc[o] += hv * W[i * OUT_DIM + o];
    }
    float* outp = hout + (size_t)d * OUT_DIM;
    #pragma unroll
    for (int o = 0; o < OUT_DIM; ++o) atomicAdd(outp + o, acc[o] * score);
}

extern "C" void kernel_launch(void* const* d_in, const int* in_sizes, int n_in,
                              void* d_out, int out_size, void* d_ws, size_t ws_size,
                              hipStream_t stream) {
    const float* h      = (const float*)d_in[0];
    const float* he     = (const float*)d_in[1];
    const float* Ws     = (const float*)d_in[2];
    const float* Wa     = (const float*)d_in[3];
    const float* weight = (const float*)d_in[4];
    const float* w_comp = (const float*)d_in[5];
    const int*   src    = (const int*)d_in[6];
    const int*   dst    = (const int*)d_in[7];
    const int*   rel    = (const int*)d_in[8];
    float* hout = (float*)d_out;

    // ws layout (float offsets)
    const size_t OFF_WREL   = 0;         // 23040 f
    const size_t OFF_AVEC   = 23040;     // 48 f (+16 pad)
    const size_t OFF_S13    = 23104;     // 100000 f
    const size_t OFF_CNT    = 123104;    // 50000 i
    const size_t OFF_BUCKET = 173104;    // N*CAP uint2 (8B aligned)
    const size_t NEED_BUCKET = OFF_BUCKET * 4 + (size_t)N_NODES * CAP * sizeof(uint2);

    float* wsf  = (float*)d_ws;
    float* Wrel = wsf + OFF_WREL;
    float* avec = wsf + OFF_AVEC;
    float2* s13 = (float2*)(wsf + OFF_S13);
    int* cnt    = (int*)(wsf + OFF_CNT);

    if (ws_size >= NEED_BUCKET) {
        uint2* bucket = (uint2*)(wsf + OFF_BUCKET);

        setup_kernel<<<PREP_BLOCKS + DOTS_BLOCKS + ZERO_BLOCKS + HZ_BLOCKS, 256, 0, stream>>>(
            Ws, Wa, weight, w_comp, h, Wrel, avec, s13, cnt, hout);
        route_kernel<<<N_EDGES / 256, 256, 0, stream>>>(
            h, he, src, dst, rel, Wrel, avec, s13, cnt, bucket, hout);
        reduce_bmm_kernel<<<(N_NODES + NODES_PER_RBLK - 1) / NODES_PER_RBLK, 1024,
                            N_RELS * LDS_STRIDE * sizeof(float), stream>>>(
            h, Wrel, bucket, cnt, hout);
    } else {
        hipMemsetAsync(d_out, 0, (size_t)out_size * sizeof(float), stream);
        int total = N_RELS * IN_DIM * OUT_DIM + 48;
        prep_kernel<<<(total + 255) / 256, 256, 0, stream>>>(Ws, Wa, weight, w_comp, Wrel, avec);
        edge_atomic_kernel<<<(N_EDGES + 255) / 256, 256, 0, stream>>>(
            h, he, src, dst, rel, Wrel, avec, hout);
    }
}